// Round 2
// baseline (545.873 us; speedup 1.0000x reference)
//
#include <hip/hip_runtime.h>

// Self_Attn: B=4, C=64, H=W=64 (N=4096), E=8.
// Outputs: y [4,64,64,64] then beta [4,4096,4096], concatenated flat fp32.
// Roofline: beta write 268 MB -> ~43 us; attn VALU ~27 us; proj+out ~7 us.
// Timed region also contains one ~170 us harness poison fill (invariant).
// R4 -> R5: R4's split/occupancy fix moved dur only -10 us => attn is NOT
// latency-bound; theory now: beta store pattern (4 B/lane, 256 B/wave burst,
// 16 KB stride between bursts) wrecks DRAM write locality. Pass C now gives
// each lane 4 consecutive j (VPT=4): float4 stores -> 1 KB contiguous per
// store instruction, 4 KB per block per i-row, 128 sequential rows per block.
// v-reduce via per-thread accumulators + atomicAdd (no LDS, no barriers).

namespace {
constexpr int Bb = 4;
constexpr int Cc = 64;
constexpr int Nn = 4096;            // H*W
constexpr int Ee = 8;               // C/8
constexpr int COLS = 64;            // pass-B: columns (j) per block wave
constexpr int SPLIT_B = 4;          // pass-B i-splits
constexpr int CHUNK_B = Nn / SPLIT_B;
constexpr int WB = 8;               // pass-B waves per block
constexpr int ISB = CHUNK_B / WB;   // 128 i per pass-B wave
// pass C geometry
constexpr int VPT = 4;              // consecutive j per lane
constexpr int TC = 256;             // threads per pass-C block (4 waves)
constexpr int JW = TC * VPT;        // 1024 j per block
constexpr int JGROUPS = Nn / JW;    // 4
constexpr int SC = 32;              // pass-C i-splits
constexpr int IC = Nn / SC;         // 128 i per pass-C block
constexpr float LOG2E = 1.4426950408889634f;
}

typedef float f4v __attribute__((ext_vector_type(4)));

#if defined(__has_builtin)
#if __has_builtin(__builtin_amdgcn_exp2f)
#define EXP2F(x) __builtin_amdgcn_exp2f(x)
#endif
#endif
#ifndef EXP2F
#define EXP2F(x) exp2f(x)
#endif

// ---------------- Kernel 1: f/g/h projections (+ zero v) --------------------
// f[b][n][e] = sum_c Wk[e][c] x[b][c][n] + bk[e]   (same for g<-Wq, h<-Wv)
// Layout [b][n][e] so attn kernels read 32B-contiguous rows.
__global__ __launch_bounds__(256) void proj_kernel(
    const float* __restrict__ x,
    const float* __restrict__ Wk, const float* __restrict__ bk,
    const float* __restrict__ Wq, const float* __restrict__ bq,
    const float* __restrict__ Wv, const float* __restrict__ bv,
    float* __restrict__ fo, float* __restrict__ go, float* __restrict__ ho,
    float* __restrict__ v_zero)
{
    __shared__ float wk[Ee * Cc], wq[Ee * Cc], wv[Ee * Cc];
    __shared__ float sb[3 * Ee];
    const int t = threadIdx.x;
    for (int i = t; i < Ee * Cc; i += 256) { wk[i] = Wk[i]; wq[i] = Wq[i]; wv[i] = Wv[i]; }
    if (t < Ee) { sb[t] = bk[t]; sb[Ee + t] = bq[t]; sb[2 * Ee + t] = bv[t]; }
    __syncthreads();

    const int gidx = blockIdx.x * 256 + t;     // b*N + n
    const int b = gidx >> 12;
    const int n = gidx & (Nn - 1);

    // zero the v accumulator buffer (beta_kernel atomically adds into it)
    float4* vz = (float4*)(v_zero + (size_t)gidx * Ee);
    vz[0] = make_float4(0.f, 0.f, 0.f, 0.f);
    vz[1] = make_float4(0.f, 0.f, 0.f, 0.f);

    float af[Ee], ag[Ee], ah[Ee];
#pragma unroll
    for (int e = 0; e < Ee; e++) { af[e] = sb[e]; ag[e] = sb[Ee + e]; ah[e] = sb[2 * Ee + e]; }

    const float* xp = x + (size_t)b * Cc * Nn + n;
#pragma unroll 4
    for (int c = 0; c < Cc; c++) {
        const float xv = xp[(size_t)c * Nn];   // coalesced across lanes
#pragma unroll
        for (int e = 0; e < Ee; e++) {
            af[e] = fmaf(wk[e * Cc + c], xv, af[e]);
            ag[e] = fmaf(wq[e * Cc + c], xv, ag[e]);
            ah[e] = fmaf(wv[e * Cc + c], xv, ah[e]);
        }
    }
    float4* fp = (float4*)(fo + (size_t)gidx * Ee);
    float4* gp = (float4*)(go + (size_t)gidx * Ee);
    float4* hp = (float4*)(ho + (size_t)gidx * Ee);
    fp[0] = make_float4(af[0], af[1], af[2], af[3]);
    fp[1] = make_float4(af[4], af[5], af[6], af[7]);
    gp[0] = make_float4(ag[0], ag[1], ag[2], ag[3]);
    gp[1] = make_float4(ag[4], ag[5], ag[6], ag[7]);
    hp[0] = make_float4(ah[0], ah[1], ah[2], ah[3]);
    hp[1] = make_float4(ah[4], ah[5], ah[6], ah[7]);
}

// ---------------- Kernel 2a: partial exp-sums -------------------------------
// Block covers (b, 64 cols, 1/SPLIT_B of the i range). No max-pass: softmax is
// shift-invariant and |s| small enough for fp32 (verified passing).
// g is pre-scaled by log2e so exp(s) = exp2(dot) = one v_exp_f32.
__global__ __launch_bounds__(512, 8) void sums_kernel(
    const float* __restrict__ f, const float* __restrict__ g,
    float* __restrict__ sums_part)
{
    const int b = blockIdx.x >> 8;
    const int jbase = ((blockIdx.x >> 2) & 63) * COLS;
    const int si = blockIdx.x & 3;
    const int t = threadIdx.x;
    const int lane = t & 63;
    const int w = __builtin_amdgcn_readfirstlane(t >> 6);
    const int j = jbase + lane;

    const float4* gp = (const float4*)(g + ((size_t)b * Nn + j) * Ee);
    const float4 g0 = gp[0], g1 = gp[1];
    const float gq[Ee] = {g0.x * LOG2E, g0.y * LOG2E, g0.z * LOG2E, g0.w * LOG2E,
                          g1.x * LOG2E, g1.y * LOG2E, g1.z * LOG2E, g1.w * LOG2E};

    const float* fb = f + (size_t)b * Nn * Ee;
    const int i0 = si * CHUNK_B + w * ISB;

    float sum = 0.f;
#pragma unroll 4
    for (int ii = 0; ii < ISB; ii++) {
        const float4* fr = (const float4*)(fb + (size_t)(i0 + ii) * Ee);
        const float4 a0 = fr[0], a1 = fr[1];
        float sA = a0.x * gq[0];
        sA = fmaf(a0.y, gq[1], sA); sA = fmaf(a0.z, gq[2], sA); sA = fmaf(a0.w, gq[3], sA);
        float sB = a1.x * gq[4];
        sB = fmaf(a1.y, gq[5], sB); sB = fmaf(a1.z, gq[6], sB); sB = fmaf(a1.w, gq[7], sB);
        sum += EXP2F(sA + sB);
    }
    __shared__ float red[WB][COLS];
    red[w][lane] = sum;
    __syncthreads();
    if (t < COLS) {
        float sf = 0.f;
#pragma unroll
        for (int ww = 0; ww < WB; ww++) sf += red[ww][t];
        sums_part[(size_t)si * (Bb * Nn) + (size_t)b * Nn + jbase + t] = sf;
    }
}

// ---------------- Kernel 2b: beta + v (atomic) ------------------------------
// Each lane owns VPT=4 consecutive j (g rows in registers). Per i: one
// wave-uniform f-row + h-row load, 4 dots, one float4 nontemporal store
// (1 KB contiguous per wave store). Per-thread v accumulators atomically
// added at the end. No LDS, no barriers.
__global__ __launch_bounds__(TC, 4) void beta_kernel(
    const float* __restrict__ f, const float* __restrict__ g,
    const float* __restrict__ h, const float* __restrict__ sums_part,
    float* __restrict__ beta, float* __restrict__ v_out)
{
    const int blk = blockIdx.x;                 // [0, Bb*JGROUPS*SC)
    const int b  = blk >> 7;                    // JGROUPS*SC = 128
    const int jg = (blk >> 5) & (JGROUPS - 1);
    const int s  = blk & (SC - 1);
    const int t  = threadIdx.x;
    const int j0 = jg * JW + t * VPT;           // first of my 4 j's

    // g[j0..j0+3][0..7] -> 32 regs, scaled by log2e
    float gq[VPT][Ee];
    {
        const float* gp = g + ((size_t)b * Nn + j0) * Ee;
#pragma unroll
        for (int jj = 0; jj < VPT; jj++) {
            const float4 a0 = ((const float4*)(gp + jj * Ee))[0];
            const float4 a1 = ((const float4*)(gp + jj * Ee))[1];
            gq[jj][0] = a0.x * LOG2E; gq[jj][1] = a0.y * LOG2E;
            gq[jj][2] = a0.z * LOG2E; gq[jj][3] = a0.w * LOG2E;
            gq[jj][4] = a1.x * LOG2E; gq[jj][5] = a1.y * LOG2E;
            gq[jj][6] = a1.z * LOG2E; gq[jj][7] = a1.w * LOG2E;
        }
    }

    float inv[VPT];
#pragma unroll
    for (int jj = 0; jj < VPT; jj++) {
        float sf = 0.f;
#pragma unroll
        for (int s2 = 0; s2 < SPLIT_B; s2++)
            sf += sums_part[(size_t)s2 * (Bb * Nn) + (size_t)b * Nn + j0 + jj];
        inv[jj] = 1.0f / sf;
    }

    const float* fb = f + (size_t)b * Nn * Ee;
    const float* hb = h + (size_t)b * Nn * Ee;
    float vacc[VPT][Ee] = {};
    float* bp = beta + (size_t)b * Nn * Nn + j0;
    const int i0 = s * IC;

    for (int ii = 0; ii < IC; ii++) {
        const int i = i0 + ii;
        // wave-uniform rows (compiler scalarizes to s_load)
        const float4 a0 = ((const float4*)(fb + (size_t)i * Ee))[0];
        const float4 a1 = ((const float4*)(fb + (size_t)i * Ee))[1];
        const float4 h0 = ((const float4*)(hb + (size_t)i * Ee))[0];
        const float4 h1 = ((const float4*)(hb + (size_t)i * Ee))[1];
        float p[VPT];
#pragma unroll
        for (int jj = 0; jj < VPT; jj++) {
            float sA = a0.x * gq[jj][0];
            sA = fmaf(a0.y, gq[jj][1], sA);
            sA = fmaf(a0.z, gq[jj][2], sA);
            sA = fmaf(a0.w, gq[jj][3], sA);
            float sB = a1.x * gq[jj][4];
            sB = fmaf(a1.y, gq[jj][5], sB);
            sB = fmaf(a1.z, gq[jj][6], sB);
            sB = fmaf(a1.w, gq[jj][7], sB);
            p[jj] = EXP2F(sA + sB) * inv[jj];
        }
        f4v pv = {p[0], p[1], p[2], p[3]};
        __builtin_nontemporal_store(pv, (f4v*)(bp + (size_t)i * Nn));
#pragma unroll
        for (int jj = 0; jj < VPT; jj++) {
            const float pj = p[jj];
            vacc[jj][0] = fmaf(h0.x, pj, vacc[jj][0]);
            vacc[jj][1] = fmaf(h0.y, pj, vacc[jj][1]);
            vacc[jj][2] = fmaf(h0.z, pj, vacc[jj][2]);
            vacc[jj][3] = fmaf(h0.w, pj, vacc[jj][3]);
            vacc[jj][4] = fmaf(h1.x, pj, vacc[jj][4]);
            vacc[jj][5] = fmaf(h1.y, pj, vacc[jj][5]);
            vacc[jj][6] = fmaf(h1.z, pj, vacc[jj][6]);
            vacc[jj][7] = fmaf(h1.w, pj, vacc[jj][7]);
        }
    }

    // one-shot reduction across the SC i-split blocks
    float* vp = v_out + ((size_t)b * Nn + j0) * Ee;
#pragma unroll
    for (int jj = 0; jj < VPT; jj++)
#pragma unroll
        for (int e = 0; e < Ee; e++)
            atomicAdd(vp + jj * Ee + e, vacc[jj][e]);
}

// ---------------- Kernel 3: o = Wo v + bo; y = leakyrelu(gamma*o + x) -------
__global__ __launch_bounds__(256) void out_kernel(
    const float* __restrict__ v, const float* __restrict__ Wo,
    const float* __restrict__ bo, const float* __restrict__ x,
    const float* __restrict__ gamma_p, float* __restrict__ y)
{
    __shared__ float wo[Cc * Ee];   // Wo[c][e] row-major
    __shared__ float sbo[Cc];
    const int t = threadIdx.x;
    for (int i = t; i < Cc * Ee; i += 256) wo[i] = Wo[i];
    if (t < Cc) sbo[t] = bo[t];
    __syncthreads();
    const float gamma = gamma_p[0];

    const int gidx = blockIdx.x * 256 + t;   // b*N + n
    const int b = gidx >> 12;
    const int n = gidx & (Nn - 1);

    const float4* vp = (const float4*)(v + (size_t)gidx * Ee);
    const float4 v0 = vp[0], v1 = vp[1];
    const float vv[Ee] = {v0.x, v0.y, v0.z, v0.w, v1.x, v1.y, v1.z, v1.w};

    const float* xp = x + (size_t)b * Cc * Nn + n;
    float* yp = y + (size_t)b * Cc * Nn + n;
#pragma unroll 4
    for (int c = 0; c < Cc; c++) {
        float o = sbo[c];
#pragma unroll
        for (int e = 0; e < Ee; e++) o = fmaf(wo[c * Ee + e], vv[e], o);
        const float t2 = fmaf(gamma, o, xp[(size_t)c * Nn]);
        yp[(size_t)c * Nn] = (t2 >= 0.f) ? t2 : 0.01f * t2;
    }
}

// ---------------- launch ----------------------------------------------------
extern "C" void kernel_launch(void* const* d_in, const int* in_sizes, int n_in,
                              void* d_out, int out_size, void* d_ws, size_t ws_size,
                              hipStream_t stream)
{
    const float* x     = (const float*)d_in[0];
    const float* Wk    = (const float*)d_in[1];
    const float* bk    = (const float*)d_in[2];
    const float* Wq    = (const float*)d_in[3];
    const float* bq    = (const float*)d_in[4];
    const float* Wv    = (const float*)d_in[5];
    const float* bv    = (const float*)d_in[6];
    const float* Wo    = (const float*)d_in[7];
    const float* bo    = (const float*)d_in[8];
    const float* gamma = (const float*)d_in[9];

    float* y    = (float*)d_out;
    float* beta = y + (size_t)Bb * Cc * Nn;   // out tuple: y then beta

    float* f = (float*)d_ws;                          // [B][N][E]: 512 KB
    float* g = f + (size_t)Bb * Nn * Ee;              // 512 KB
    float* h = g + (size_t)Bb * Nn * Ee;              // 512 KB
    float* sums_part = h + (size_t)Bb * Nn * Ee;      // [SPLIT_B][B*N]: 256 KB
    float* v = sums_part + (size_t)SPLIT_B * Bb * Nn; // [B*N][E]: 512 KB

    proj_kernel<<<Bb * Nn / 256, 256, 0, stream>>>(x, Wk, bk, Wq, bq, Wv, bv, f, g, h, v);
    sums_kernel<<<Bb * (Nn / COLS) * SPLIT_B, 512, 0, stream>>>(f, g, sums_part);
    beta_kernel<<<Bb * JGROUPS * SC, TC, 0, stream>>>(f, g, h, sums_part, beta, v);
    out_kernel<<<Bb * Nn / 256, 256, 0, stream>>>(v, Wo, bo, x, gamma, y);
}

// Round 3
// 361.717 us; speedup vs baseline: 1.5091x; 1.5091x over previous
//
#include <hip/hip_runtime.h>

// Self_Attn: B=4, C=64, H=W=64 (N=4096), E=8.
// Outputs: y [4,64,64,64] then beta [4,4096,4096], concatenated flat fp32.
// Roofline: beta write 268 MB -> ~43 us; attn VALU ~40 us; proj+out ~10 us.
// Timed region also contains one ~170 us harness poison fill (invariant).
// R5 -> R6: R5's beta_kernel measured 250 us @ 1.6 TB/s, VALUBusy 8%,
// occupancy 14%, WRITE_SIZE 403 MB (1.5x amplification with nontemporal).
// => write-pipeline was latency-bound (8 waves/CU, no unroll, vmcnt waits
// include prior nt-store completion). The harness fill kernel proves 4 KB
// contiguous per block-step + large strides = 6.4 TB/s. So: move the
// v-numerator into pass B; pass C becomes fill-isomorphic: 256 thr x
// float4/thread = 4 KB/block/i, f-rows in LDS (no global loads in loop),
// plain stores (no nt), 8 blocks/CU, grid 2048.

namespace {
constexpr int Bb = 4;
constexpr int Cc = 64;
constexpr int Nn = 4096;            // H*W
constexpr int Ee = 8;               // C/8
// pass B (sums + v numerator)
constexpr int COLS = 64;            // columns (j) per block wave
constexpr int SPLIT_B = 4;          // i-splits
constexpr int CHUNK_B = Nn / SPLIT_B;
constexpr int WB = 8;               // waves per block
constexpr int ISB = CHUNK_B / WB;   // 128 i per wave
// pass C (beta writer)
constexpr int VPT = 4;              // consecutive j per lane
constexpr int TC = 256;             // threads per block
constexpr int JBLK = TC * VPT;      // 1024 j per block (quarter row)
constexpr int JQ = Nn / JBLK;       // 4
constexpr int ITILE = 32;           // i-rows per block
constexpr int SI = Nn / ITILE;      // 128
constexpr float LOG2E = 1.4426950408889634f;
}

typedef float f4v __attribute__((ext_vector_type(4)));

#if defined(__has_builtin)
#if __has_builtin(__builtin_amdgcn_exp2f)
#define EXP2F(x) __builtin_amdgcn_exp2f(x)
#endif
#endif
#ifndef EXP2F
#define EXP2F(x) exp2f(x)
#endif

// ---------------- Kernel 1: f/g/h projections -------------------------------
// f[b][n][e] = sum_c Wk[e][c] x[b][c][n] + bk[e]   (same for g<-Wq, h<-Wv)
// Layout [b][n][e] so attn kernels read 32B-contiguous rows.
__global__ __launch_bounds__(256) void proj_kernel(
    const float* __restrict__ x,
    const float* __restrict__ Wk, const float* __restrict__ bk,
    const float* __restrict__ Wq, const float* __restrict__ bq,
    const float* __restrict__ Wv, const float* __restrict__ bv,
    float* __restrict__ fo, float* __restrict__ go, float* __restrict__ ho)
{
    __shared__ float wk[Ee * Cc], wq[Ee * Cc], wv[Ee * Cc];
    __shared__ float sb[3 * Ee];
    const int t = threadIdx.x;
    for (int i = t; i < Ee * Cc; i += 256) { wk[i] = Wk[i]; wq[i] = Wq[i]; wv[i] = Wv[i]; }
    if (t < Ee) { sb[t] = bk[t]; sb[Ee + t] = bq[t]; sb[2 * Ee + t] = bv[t]; }
    __syncthreads();

    const int gidx = blockIdx.x * 256 + t;     // b*N + n
    const int b = gidx >> 12;
    const int n = gidx & (Nn - 1);

    float af[Ee], ag[Ee], ah[Ee];
#pragma unroll
    for (int e = 0; e < Ee; e++) { af[e] = sb[e]; ag[e] = sb[Ee + e]; ah[e] = sb[2 * Ee + e]; }

    const float* xp = x + (size_t)b * Cc * Nn + n;
#pragma unroll 4
    for (int c = 0; c < Cc; c++) {
        const float xv = xp[(size_t)c * Nn];   // coalesced across lanes
#pragma unroll
        for (int e = 0; e < Ee; e++) {
            af[e] = fmaf(wk[e * Cc + c], xv, af[e]);
            ag[e] = fmaf(wq[e * Cc + c], xv, ag[e]);
            ah[e] = fmaf(wv[e * Cc + c], xv, ah[e]);
        }
    }
    float4* fp = (float4*)(fo + (size_t)gidx * Ee);
    float4* gp = (float4*)(go + (size_t)gidx * Ee);
    float4* hp = (float4*)(ho + (size_t)gidx * Ee);
    fp[0] = make_float4(af[0], af[1], af[2], af[3]);
    fp[1] = make_float4(af[4], af[5], af[6], af[7]);
    gp[0] = make_float4(ag[0], ag[1], ag[2], ag[3]);
    gp[1] = make_float4(ag[4], ag[5], ag[6], ag[7]);
    hp[0] = make_float4(ah[0], ah[1], ah[2], ah[7 - 3]);
    hp[1] = make_float4(ah[4], ah[5], ah[6], ah[7]);
}

// ---------------- Kernel 2a: exp-sums + v numerator -------------------------
// Block covers (b, 64 cols, 1/SPLIT_B of the i range). No max-pass: softmax is
// shift-invariant and |s| small enough for fp32 (verified passing).
// g is pre-scaled by log2e so exp(s) = exp2(dot) = one v_exp_f32.
// Also accumulates vnum[j][e] = sum_i h[i][e]*exp(s_ij) so the beta pass
// needs no h-loads / reductions / atomics.
__global__ __launch_bounds__(512, 8) void sumv_kernel(
    const float* __restrict__ f, const float* __restrict__ g,
    const float* __restrict__ h,
    float* __restrict__ sums_part, float* __restrict__ v_part)
{
    const int b = blockIdx.x >> 8;
    const int jbase = ((blockIdx.x >> 2) & 63) * COLS;
    const int si = blockIdx.x & 3;
    const int t = threadIdx.x;
    const int lane = t & 63;
    const int w = __builtin_amdgcn_readfirstlane(t >> 6);
    const int j = jbase + lane;

    const float4* gp = (const float4*)(g + ((size_t)b * Nn + j) * Ee);
    const float4 g0 = gp[0], g1 = gp[1];
    const float gq[Ee] = {g0.x * LOG2E, g0.y * LOG2E, g0.z * LOG2E, g0.w * LOG2E,
                          g1.x * LOG2E, g1.y * LOG2E, g1.z * LOG2E, g1.w * LOG2E};

    const float* fb = f + (size_t)b * Nn * Ee;
    const float* hb = h + (size_t)b * Nn * Ee;
    const int i0 = si * CHUNK_B + w * ISB;

    float sum = 0.f;
    float vacc[Ee] = {};
#pragma unroll 4
    for (int ii = 0; ii < ISB; ii++) {
        const int i = i0 + ii;
        const float4* fr = (const float4*)(fb + (size_t)i * Ee);
        const float4 a0 = fr[0], a1 = fr[1];
        float sA = a0.x * gq[0];
        sA = fmaf(a0.y, gq[1], sA); sA = fmaf(a0.z, gq[2], sA); sA = fmaf(a0.w, gq[3], sA);
        float sB = a1.x * gq[4];
        sB = fmaf(a1.y, gq[5], sB); sB = fmaf(a1.z, gq[6], sB); sB = fmaf(a1.w, gq[7], sB);
        const float e = EXP2F(sA + sB);
        sum += e;
        const float4* hr = (const float4*)(hb + (size_t)i * Ee);
        const float4 h0 = hr[0], h1 = hr[1];
        vacc[0] = fmaf(h0.x, e, vacc[0]); vacc[1] = fmaf(h0.y, e, vacc[1]);
        vacc[2] = fmaf(h0.z, e, vacc[2]); vacc[3] = fmaf(h0.w, e, vacc[3]);
        vacc[4] = fmaf(h1.x, e, vacc[4]); vacc[5] = fmaf(h1.y, e, vacc[5]);
        vacc[6] = fmaf(h1.z, e, vacc[6]); vacc[7] = fmaf(h1.w, e, vacc[7]);
    }

    __shared__ float red[WB][COLS];
    __shared__ float vred[WB][COLS][Ee];   // 16 KB
    red[w][lane] = sum;
    float4* vw = (float4*)&vred[w][lane][0];
    vw[0] = make_float4(vacc[0], vacc[1], vacc[2], vacc[3]);
    vw[1] = make_float4(vacc[4], vacc[5], vacc[6], vacc[7]);
    __syncthreads();
    if (t < COLS) {
        float sf = 0.f;
#pragma unroll
        for (int ww = 0; ww < WB; ww++) sf += red[ww][t];
        sums_part[(size_t)si * (Bb * Nn) + (size_t)b * Nn + jbase + t] = sf;
    }
    {
        const int col = t >> 3;       // 64 cols x 8 e == 512 threads
        const int e = t & 7;
        float acc = 0.f;
#pragma unroll
        for (int ww = 0; ww < WB; ww++) acc += vred[ww][col][e];
        v_part[(size_t)si * (Bb * Nn * Ee) +
               ((size_t)b * Nn + jbase + col) * Ee + e] = acc;
    }
}

// ---------------- Kernel 2b: pure beta writer -------------------------------
// Fill-kernel-isomorphic: per i, block writes 256 threads x float4 = 4 KB
// contiguous; f-rows staged in LDS so the steady loop has NO global loads;
// stores are independent (plain, through L2) -> vmcnt backpressure only.
__global__ __launch_bounds__(TC, 8) void beta_kernel(
    const float* __restrict__ f, const float* __restrict__ g,
    const float* __restrict__ sums_part, float* __restrict__ beta)
{
    const int blk = blockIdx.x;            // b*(JQ*SI) + jq*SI + si
    const int b  = blk >> 9;               // JQ*SI = 512
    const int jq = (blk >> 7) & (JQ - 1);
    const int si = blk & (SI - 1);
    const int t  = threadIdx.x;
    const int j0 = jq * JBLK + t * VPT;
    const int i0 = si * ITILE;

    // stage the block's f tile (ITILE rows x 8 e = 256 floats = 1 KB)
    __shared__ float fs[ITILE * Ee];
    const float* fb = f + (size_t)b * Nn * Ee;
    fs[t] = fb[(size_t)i0 * Ee + t];

    // g[j0..j0+3][0..7] -> 32 regs, scaled by log2e
    float gq[VPT][Ee];
    {
        const float* gp = g + ((size_t)b * Nn + j0) * Ee;
#pragma unroll
        for (int jj = 0; jj < VPT; jj++) {
            const float4 a0 = ((const float4*)(gp + jj * Ee))[0];
            const float4 a1 = ((const float4*)(gp + jj * Ee))[1];
            gq[jj][0] = a0.x * LOG2E; gq[jj][1] = a0.y * LOG2E;
            gq[jj][2] = a0.z * LOG2E; gq[jj][3] = a0.w * LOG2E;
            gq[jj][4] = a1.x * LOG2E; gq[jj][5] = a1.y * LOG2E;
            gq[jj][6] = a1.z * LOG2E; gq[jj][7] = a1.w * LOG2E;
        }
    }
    float inv[VPT];
#pragma unroll
    for (int jj = 0; jj < VPT; jj++) {
        float sf = 0.f;
#pragma unroll
        for (int s2 = 0; s2 < SPLIT_B; s2++)
            sf += sums_part[(size_t)s2 * (Bb * Nn) + (size_t)b * Nn + j0 + jj];
        inv[jj] = 1.0f / sf;
    }
    __syncthreads();

    float* bp = beta + (size_t)b * Nn * Nn + j0;
#pragma unroll 4
    for (int ii = 0; ii < ITILE; ii++) {
        const float4 a0 = ((const float4*)fs)[ii * 2];
        const float4 a1 = ((const float4*)fs)[ii * 2 + 1];
        float p[VPT];
#pragma unroll
        for (int jj = 0; jj < VPT; jj++) {
            float sA = a0.x * gq[jj][0];
            sA = fmaf(a0.y, gq[jj][1], sA);
            sA = fmaf(a0.z, gq[jj][2], sA);
            sA = fmaf(a0.w, gq[jj][3], sA);
            float sB = a1.x * gq[jj][4];
            sB = fmaf(a1.y, gq[jj][5], sB);
            sB = fmaf(a1.z, gq[jj][6], sB);
            sB = fmaf(a1.w, gq[jj][7], sB);
            p[jj] = EXP2F(sA + sB) * inv[jj];
        }
        f4v pv = {p[0], p[1], p[2], p[3]};
        *(f4v*)(bp + (size_t)(i0 + ii) * Nn) = pv;   // 4 KB contiguous per block
    }
}

// ---------------- Kernel 3: o = Wo v + bo; y = leakyrelu(gamma*o + x) -------
__global__ __launch_bounds__(256) void out_kernel(
    const float* __restrict__ v_part, const float* __restrict__ sums_part,
    const float* __restrict__ Wo, const float* __restrict__ bo,
    const float* __restrict__ x, const float* __restrict__ gamma_p,
    float* __restrict__ y)
{
    __shared__ float wo[Cc * Ee];   // Wo[c][e] row-major
    __shared__ float sbo[Cc];
    const int t = threadIdx.x;
    for (int i = t; i < Cc * Ee; i += 256) wo[i] = Wo[i];
    if (t < Cc) sbo[t] = bo[t];
    __syncthreads();
    const float gamma = gamma_p[0];

    const int gidx = blockIdx.x * 256 + t;   // b*N + n  (n == j)
    const int b = gidx >> 12;
    const int n = gidx & (Nn - 1);

    float sf = 0.f;
#pragma unroll
    for (int s2 = 0; s2 < SPLIT_B; s2++)
        sf += sums_part[(size_t)s2 * (Bb * Nn) + gidx];
    const float inv = 1.0f / sf;

    float vv[Ee] = {};
#pragma unroll
    for (int s2 = 0; s2 < SPLIT_B; s2++) {
        const float4* vp = (const float4*)(v_part + (size_t)s2 * (Bb * Nn * Ee) + (size_t)gidx * Ee);
        const float4 v0 = vp[0], v1 = vp[1];
        vv[0] += v0.x; vv[1] += v0.y; vv[2] += v0.z; vv[3] += v0.w;
        vv[4] += v1.x; vv[5] += v1.y; vv[6] += v1.z; vv[7] += v1.w;
    }
#pragma unroll
    for (int e = 0; e < Ee; e++) vv[e] *= inv;

    const float* xp = x + (size_t)b * Cc * Nn + n;
    float* yp = y + (size_t)b * Cc * Nn + n;
#pragma unroll 4
    for (int c = 0; c < Cc; c++) {
        float o = sbo[c];
#pragma unroll
        for (int e = 0; e < Ee; e++) o = fmaf(wo[c * Ee + e], vv[e], o);
        const float t2 = fmaf(gamma, o, xp[(size_t)c * Nn]);
        yp[(size_t)c * Nn] = (t2 >= 0.f) ? t2 : 0.01f * t2;
    }
}

// ---------------- launch ----------------------------------------------------
extern "C" void kernel_launch(void* const* d_in, const int* in_sizes, int n_in,
                              void* d_out, int out_size, void* d_ws, size_t ws_size,
                              hipStream_t stream)
{
    const float* x     = (const float*)d_in[0];
    const float* Wk    = (const float*)d_in[1];
    const float* bk    = (const float*)d_in[2];
    const float* Wq    = (const float*)d_in[3];
    const float* bq    = (const float*)d_in[4];
    const float* Wv    = (const float*)d_in[5];
    const float* bv    = (const float*)d_in[6];
    const float* Wo    = (const float*)d_in[7];
    const float* bo    = (const float*)d_in[8];
    const float* gamma = (const float*)d_in[9];

    float* y    = (float*)d_out;
    float* beta = y + (size_t)Bb * Cc * Nn;   // out tuple: y then beta

    float* f = (float*)d_ws;                          // [B][N][E]: 512 KB
    float* g = f + (size_t)Bb * Nn * Ee;              // 512 KB
    float* h = g + (size_t)Bb * Nn * Ee;              // 512 KB
    float* sums_part = h + (size_t)Bb * Nn * Ee;      // [SPLIT_B][B*N]: 256 KB
    float* v_part = sums_part + (size_t)SPLIT_B * Bb * Nn;  // [SPLIT_B][B*N][E]: 2 MB

    proj_kernel<<<Bb * Nn / 256, 256, 0, stream>>>(x, Wk, bk, Wq, bq, Wv, bv, f, g, h);
    sumv_kernel<<<Bb * (Nn / COLS) * SPLIT_B, 512, 0, stream>>>(f, g, h, sums_part, v_part);
    beta_kernel<<<Bb * JQ * SI, TC, 0, stream>>>(f, g, sums_part, beta);
    out_kernel<<<Bb * Nn / 256, 256, 0, stream>>>(v_part, sums_part, Wo, bo, x, gamma, y);
}

// Round 4
// 358.650 us; speedup vs baseline: 1.5220x; 1.0086x over previous
//
#include <hip/hip_runtime.h>

// Self_Attn: B=4, C=64, H=W=64 (N=4096), E=8.
// Outputs: y [4,64,64,64] then beta [4,4096,4096], concatenated flat fp32.
// Roofline: beta write 268 MB -> ~43 us; attn VALU ~40 us; proj+out ~10 us.
// Timed region also contains one ~174 us harness poison fill (invariant).
// R6 -> R7: ours ~188 us vs ~75 us model. Fill proves store BW saturates at
// ~10% occupancy -- what matters is per-stream contiguity. New beta writer:
// block = 1024 thr x 4 j = FULL row (16 KB contiguous per row), walks 32
// consecutive rows -> 512 KB perfectly sequential per block, 512 blocks.
// Denominator folded into exponent: p = exp2(f.g_hat - log2(sum)) (no mul,
// no inv regs). f-row loads are block-uniform -> s_load; zero VMEM reads in
// the steady loop. Also FIXED R5 typo: proj h wrote ah[4] into slot 3.

namespace {
constexpr int Bb = 4;
constexpr int Cc = 64;
constexpr int Nn = 4096;            // H*W
constexpr int Ee = 8;               // C/8
// pass B (sums + v numerator)
constexpr int COLS = 64;            // columns (j) per block wave
constexpr int SPLIT_B = 4;          // i-splits
constexpr int CHUNK_B = Nn / SPLIT_B;
constexpr int WB = 8;               // waves per block
constexpr int ISB = CHUNK_B / WB;   // 128 i per wave
// pass C (beta writer)
constexpr int VPT = 4;              // consecutive j per thread (float4 store)
constexpr int TCW = 1024;           // threads per block = Nn/VPT (full row)
constexpr int RPB = 32;             // consecutive rows per block
constexpr float LOG2E = 1.4426950408889634f;
}

typedef float f4v __attribute__((ext_vector_type(4)));

#if defined(__has_builtin)
#if __has_builtin(__builtin_amdgcn_exp2f)
#define EXP2F(x) __builtin_amdgcn_exp2f(x)
#endif
#endif
#ifndef EXP2F
#define EXP2F(x) exp2f(x)
#endif

// ---------------- Kernel 1: f/g/h projections -------------------------------
// f[b][n][e] = sum_c Wk[e][c] x[b][c][n] + bk[e]   (same for g<-Wq, h<-Wv)
// Layout [b][n][e] so attn kernels read 32B-contiguous rows.
__global__ __launch_bounds__(256) void proj_kernel(
    const float* __restrict__ x,
    const float* __restrict__ Wk, const float* __restrict__ bk,
    const float* __restrict__ Wq, const float* __restrict__ bq,
    const float* __restrict__ Wv, const float* __restrict__ bv,
    float* __restrict__ fo, float* __restrict__ go, float* __restrict__ ho)
{
    __shared__ float wk[Ee * Cc], wq[Ee * Cc], wv[Ee * Cc];
    __shared__ float sb[3 * Ee];
    const int t = threadIdx.x;
    for (int i = t; i < Ee * Cc; i += 256) { wk[i] = Wk[i]; wq[i] = Wq[i]; wv[i] = Wv[i]; }
    if (t < Ee) { sb[t] = bk[t]; sb[Ee + t] = bq[t]; sb[2 * Ee + t] = bv[t]; }
    __syncthreads();

    const int gidx = blockIdx.x * 256 + t;     // b*N + n
    const int b = gidx >> 12;
    const int n = gidx & (Nn - 1);

    float af[Ee], ag[Ee], ah[Ee];
#pragma unroll
    for (int e = 0; e < Ee; e++) { af[e] = sb[e]; ag[e] = sb[Ee + e]; ah[e] = sb[2 * Ee + e]; }

    const float* xp = x + (size_t)b * Cc * Nn + n;
#pragma unroll 4
    for (int c = 0; c < Cc; c++) {
        const float xv = xp[(size_t)c * Nn];   // coalesced across lanes
#pragma unroll
        for (int e = 0; e < Ee; e++) {
            af[e] = fmaf(wk[e * Cc + c], xv, af[e]);
            ag[e] = fmaf(wq[e * Cc + c], xv, ag[e]);
            ah[e] = fmaf(wv[e * Cc + c], xv, ah[e]);
        }
    }
    float4* fp = (float4*)(fo + (size_t)gidx * Ee);
    float4* gp = (float4*)(go + (size_t)gidx * Ee);
    float4* hp = (float4*)(ho + (size_t)gidx * Ee);
    fp[0] = make_float4(af[0], af[1], af[2], af[3]);
    fp[1] = make_float4(af[4], af[5], af[6], af[7]);
    gp[0] = make_float4(ag[0], ag[1], ag[2], ag[3]);
    gp[1] = make_float4(ag[4], ag[5], ag[6], ag[7]);
    hp[0] = make_float4(ah[0], ah[1], ah[2], ah[3]);
    hp[1] = make_float4(ah[4], ah[5], ah[6], ah[7]);
}

// ---------------- Kernel 2a: exp-sums + v numerator -------------------------
// Block covers (b, 64 cols, 1/SPLIT_B of the i range). No max-pass: softmax is
// shift-invariant and |s| small enough for fp32 (verified passing).
// g is pre-scaled by log2e so exp(s) = exp2(dot) = one v_exp_f32.
// Also accumulates vnum[j][e] = sum_i h[i][e]*exp(s_ij) so the beta pass
// needs no h-loads / reductions / atomics.
__global__ __launch_bounds__(512, 8) void sumv_kernel(
    const float* __restrict__ f, const float* __restrict__ g,
    const float* __restrict__ h,
    float* __restrict__ sums_part, float* __restrict__ v_part)
{
    const int b = blockIdx.x >> 8;
    const int jbase = ((blockIdx.x >> 2) & 63) * COLS;
    const int si = blockIdx.x & 3;
    const int t = threadIdx.x;
    const int lane = t & 63;
    const int w = __builtin_amdgcn_readfirstlane(t >> 6);
    const int j = jbase + lane;

    const float4* gp = (const float4*)(g + ((size_t)b * Nn + j) * Ee);
    const float4 g0 = gp[0], g1 = gp[1];
    const float gq[Ee] = {g0.x * LOG2E, g0.y * LOG2E, g0.z * LOG2E, g0.w * LOG2E,
                          g1.x * LOG2E, g1.y * LOG2E, g1.z * LOG2E, g1.w * LOG2E};

    const float* fb = f + (size_t)b * Nn * Ee;
    const float* hb = h + (size_t)b * Nn * Ee;
    const int i0 = si * CHUNK_B + w * ISB;

    float sum = 0.f;
    float vacc[Ee] = {};
#pragma unroll 4
    for (int ii = 0; ii < ISB; ii++) {
        const int i = i0 + ii;
        const float4* fr = (const float4*)(fb + (size_t)i * Ee);
        const float4 a0 = fr[0], a1 = fr[1];
        float sA = a0.x * gq[0];
        sA = fmaf(a0.y, gq[1], sA); sA = fmaf(a0.z, gq[2], sA); sA = fmaf(a0.w, gq[3], sA);
        float sB = a1.x * gq[4];
        sB = fmaf(a1.y, gq[5], sB); sB = fmaf(a1.z, gq[6], sB); sB = fmaf(a1.w, gq[7], sB);
        const float e = EXP2F(sA + sB);
        sum += e;
        const float4* hr = (const float4*)(hb + (size_t)i * Ee);
        const float4 h0 = hr[0], h1 = hr[1];
        vacc[0] = fmaf(h0.x, e, vacc[0]); vacc[1] = fmaf(h0.y, e, vacc[1]);
        vacc[2] = fmaf(h0.z, e, vacc[2]); vacc[3] = fmaf(h0.w, e, vacc[3]);
        vacc[4] = fmaf(h1.x, e, vacc[4]); vacc[5] = fmaf(h1.y, e, vacc[5]);
        vacc[6] = fmaf(h1.z, e, vacc[6]); vacc[7] = fmaf(h1.w, e, vacc[7]);
    }

    __shared__ float red[WB][COLS];
    __shared__ float vred[WB][COLS][Ee];   // 16 KB
    red[w][lane] = sum;
    float4* vw = (float4*)&vred[w][lane][0];
    vw[0] = make_float4(vacc[0], vacc[1], vacc[2], vacc[3]);
    vw[1] = make_float4(vacc[4], vacc[5], vacc[6], vacc[7]);
    __syncthreads();
    if (t < COLS) {
        float sf = 0.f;
#pragma unroll
        for (int ww = 0; ww < WB; ww++) sf += red[ww][t];
        sums_part[(size_t)si * (Bb * Nn) + (size_t)b * Nn + jbase + t] = sf;
    }
    {
        const int col = t >> 3;       // 64 cols x 8 e == 512 threads
        const int e = t & 7;
        float acc = 0.f;
#pragma unroll
        for (int ww = 0; ww < WB; ww++) acc += vred[ww][col][e];
        v_part[(size_t)si * (Bb * Nn * Ee) +
               ((size_t)b * Nn + jbase + col) * Ee + e] = acc;
    }
}

// ---------------- Kernel 2b: pure beta writer (full-row, contiguous) --------
// Block = 1024 threads x 4 j = one full beta row per store step (16 KB
// contiguous), walking 32 consecutive rows -> 512 KB sequential per block.
// p = exp2(f . g_hat - log2(sum)): denominator folded into the exponent.
// f-row loads are block-uniform -> scalarized; zero per-lane loads in loop.
__global__ __launch_bounds__(TCW, 4) void beta_kernel(
    const float* __restrict__ f, const float* __restrict__ g,
    const float* __restrict__ sums_part, float* __restrict__ beta)
{
    const int blk = blockIdx.x;            // b*(Nn/RPB) + row-group
    const int b  = blk >> 7;               // Nn/RPB = 128
    const int i0 = (blk & 127) * RPB;
    const int t  = threadIdx.x;
    const int j0 = t * VPT;

    // g[j0..j0+3][0..7] -> 32 regs scaled by log2e; c_j = -log2(sum_j)
    float gq[VPT][Ee], cj[VPT];
    {
        const float* gp = g + ((size_t)b * Nn + j0) * Ee;
#pragma unroll
        for (int jj = 0; jj < VPT; jj++) {
            const float4 a0 = ((const float4*)(gp + jj * Ee))[0];
            const float4 a1 = ((const float4*)(gp + jj * Ee))[1];
            gq[jj][0] = a0.x * LOG2E; gq[jj][1] = a0.y * LOG2E;
            gq[jj][2] = a0.z * LOG2E; gq[jj][3] = a0.w * LOG2E;
            gq[jj][4] = a1.x * LOG2E; gq[jj][5] = a1.y * LOG2E;
            gq[jj][6] = a1.z * LOG2E; gq[jj][7] = a1.w * LOG2E;
        }
#pragma unroll
        for (int jj = 0; jj < VPT; jj++) {
            float sf = 0.f;
#pragma unroll
            for (int s2 = 0; s2 < SPLIT_B; s2++)
                sf += sums_part[(size_t)s2 * (Bb * Nn) + (size_t)b * Nn + j0 + jj];
            cj[jj] = -log2f(sf);
        }
    }

    const float* fb = f + (size_t)b * Nn * Ee;
    float* bp = beta + (size_t)b * Nn * Nn + j0;
#pragma unroll 2
    for (int ii = 0; ii < RPB; ii++) {
        const int i = i0 + ii;
        // block-uniform row -> s_load, broadcast
        const float4 a0 = ((const float4*)(fb + (size_t)i * Ee))[0];
        const float4 a1 = ((const float4*)(fb + (size_t)i * Ee))[1];
        float p[VPT];
#pragma unroll
        for (int jj = 0; jj < VPT; jj++) {
            float sA = a0.x * gq[jj][0];
            sA = fmaf(a0.y, gq[jj][1], sA);
            sA = fmaf(a0.z, gq[jj][2], sA);
            sA = fmaf(a0.w, gq[jj][3], sA);
            float sB = fmaf(a1.x, gq[jj][4], cj[jj]);
            sB = fmaf(a1.y, gq[jj][5], sB);
            sB = fmaf(a1.z, gq[jj][6], sB);
            sB = fmaf(a1.w, gq[jj][7], sB);
            p[jj] = EXP2F(sA + sB);
        }
        f4v pv = {p[0], p[1], p[2], p[3]};
        *(f4v*)(bp + (size_t)i * Nn) = pv;   // 16 KB contiguous per block-row
    }
}

// ---------------- Kernel 3: o = Wo v + bo; y = leakyrelu(gamma*o + x) -------
__global__ __launch_bounds__(256) void out_kernel(
    const float* __restrict__ v_part, const float* __restrict__ sums_part,
    const float* __restrict__ Wo, const float* __restrict__ bo,
    const float* __restrict__ x, const float* __restrict__ gamma_p,
    float* __restrict__ y)
{
    __shared__ float wo[Cc * Ee];   // Wo[c][e] row-major
    __shared__ float sbo[Cc];
    const int t = threadIdx.x;
    for (int i = t; i < Cc * Ee; i += 256) wo[i] = Wo[i];
    if (t < Cc) sbo[t] = bo[t];
    __syncthreads();
    const float gamma = gamma_p[0];

    const int gidx = blockIdx.x * 256 + t;   // b*N + n  (n == j)
    const int b = gidx >> 12;
    const int n = gidx & (Nn - 1);

    float sf = 0.f;
#pragma unroll
    for (int s2 = 0; s2 < SPLIT_B; s2++)
        sf += sums_part[(size_t)s2 * (Bb * Nn) + gidx];
    const float inv = 1.0f / sf;

    float vv[Ee] = {};
#pragma unroll
    for (int s2 = 0; s2 < SPLIT_B; s2++) {
        const float4* vp = (const float4*)(v_part + (size_t)s2 * (Bb * Nn * Ee) + (size_t)gidx * Ee);
        const float4 v0 = vp[0], v1 = vp[1];
        vv[0] += v0.x; vv[1] += v0.y; vv[2] += v0.z; vv[3] += v0.w;
        vv[4] += v1.x; vv[5] += v1.y; vv[6] += v1.z; vv[7] += v1.w;
    }
#pragma unroll
    for (int e = 0; e < Ee; e++) vv[e] *= inv;

    const float* xp = x + (size_t)b * Cc * Nn + n;
    float* yp = y + (size_t)b * Cc * Nn + n;
#pragma unroll 4
    for (int c = 0; c < Cc; c++) {
        float o = sbo[c];
#pragma unroll
        for (int e = 0; e < Ee; e++) o = fmaf(wo[c * Ee + e], vv[e], o);
        const float t2 = fmaf(gamma, o, xp[(size_t)c * Nn]);
        yp[(size_t)c * Nn] = (t2 >= 0.f) ? t2 : 0.01f * t2;
    }
}

// ---------------- launch ----------------------------------------------------
extern "C" void kernel_launch(void* const* d_in, const int* in_sizes, int n_in,
                              void* d_out, int out_size, void* d_ws, size_t ws_size,
                              hipStream_t stream)
{
    const float* x     = (const float*)d_in[0];
    const float* Wk    = (const float*)d_in[1];
    const float* bk    = (const float*)d_in[2];
    const float* Wq    = (const float*)d_in[3];
    const float* bq    = (const float*)d_in[4];
    const float* Wv    = (const float*)d_in[5];
    const float* bv    = (const float*)d_in[6];
    const float* Wo    = (const float*)d_in[7];
    const float* bo    = (const float*)d_in[8];
    const float* gamma = (const float*)d_in[9];

    float* y    = (float*)d_out;
    float* beta = y + (size_t)Bb * Cc * Nn;   // out tuple: y then beta

    float* f = (float*)d_ws;                          // [B][N][E]: 512 KB
    float* g = f + (size_t)Bb * Nn * Ee;              // 512 KB
    float* h = g + (size_t)Bb * Nn * Ee;              // 512 KB
    float* sums_part = h + (size_t)Bb * Nn * Ee;      // [SPLIT_B][B*N]: 256 KB
    float* v_part = sums_part + (size_t)SPLIT_B * Bb * Nn;  // [SPLIT_B][B*N][E]: 2 MB

    proj_kernel<<<Bb * Nn / 256, 256, 0, stream>>>(x, Wk, bk, Wq, bq, Wv, bv, f, g, h);
    sumv_kernel<<<Bb * (Nn / COLS) * SPLIT_B, 512, 0, stream>>>(f, g, h, sums_part, v_part);
    beta_kernel<<<Bb * (Nn / RPB), TCW, 0, stream>>>(f, g, sums_part, beta);
    out_kernel<<<Bb * Nn / 256, 256, 0, stream>>>(v_part, sums_part, Wo, bo, x, gamma, y);
}